// Round 1
// baseline (75.640 us; speedup 1.0000x reference)
//
#include <hip/hip_runtime.h>
#include <hip/hip_bf16.h>

#define NI 256
#define NT 256
#define NL 25
#define NE 128
#define NHW 49
#define NPAD 64
#define NTL (NT*NL)   // 6400

#define G 4           // images per workgroup
#define CH_TEXTS 64   // texts per chunk (4 chunks)
#define CH_ROWS 1600  // CH_TEXTS * NL
#define QUADS 25      // CH_ROWS / 64
#define BROW 136      // LDS row stride in bf16 (272 B = 256 + 16 pad -> conflict-free b128)

typedef __attribute__((ext_vector_type(8))) short bf16x8;
typedef __attribute__((ext_vector_type(4))) float f32x4;

struct bf4 { __hip_bfloat16 x, y, z, w; };
struct bf2 { __hip_bfloat16 x, y; };

// ---- Kernel 1: gather text features -> bf16 TF[6400][128] ----
__global__ __launch_bounds__(256) void gather_tf_kernel(
    const float* __restrict__ emb, const int* __restrict__ text,
    __hip_bfloat16* __restrict__ tf)
{
    int idx = blockIdx.x * 256 + threadIdx.x;   // 0 .. 204799 (4 elems each)
    int tl = idx >> 5;
    int q  = idx & 31;
    int tok = text[tl];
    float4 v = *reinterpret_cast<const float4*>(emb + (size_t)tok * NE + q * 4);
    bf4 o { __float2bfloat16(v.x), __float2bfloat16(v.y),
            __float2bfloat16(v.z), __float2bfloat16(v.w) };
    *reinterpret_cast<bf4*>(tf + (size_t)tl * NE + q * 4) = o;
}

// ---- Kernel 2: transpose image features -> bf16 P[256][64][128] (patch-major, zero-padded) ----
__global__ __launch_bounds__(256) void prep_img_kernel(
    const float* __restrict__ img, __hip_bfloat16* __restrict__ P)
{
    __shared__ float tile[NE * NHW];   // 6272 f32
    int i = blockIdx.x;
    const float* src = img + (size_t)i * NE * NHW;
    for (int idx = threadIdx.x; idx < NE * NHW; idx += 256) tile[idx] = src[idx];
    __syncthreads();
    __hip_bfloat16* dst = P + (size_t)i * NPAD * NE;
    for (int idx = threadIdx.x; idx < NPAD * NE / 2; idx += 256) {
        int p = idx >> 6;
        int e = (idx & 63) * 2;
        bf2 o;
        if (p < NHW) {
            o.x = __float2bfloat16(tile[e * NHW + p]);
            o.y = __float2bfloat16(tile[(e + 1) * NHW + p]);
        } else {
            o.x = __float2bfloat16(0.f);
            o.y = o.x;
        }
        *reinterpret_cast<bf2*>(dst + p * NE + e) = o;
    }
}

// ---- Kernel 3: fused MFMA GEMM + max-over-patches + sum-over-words + scale ----
__global__ __launch_bounds__(512, 2) void match_kernel(
    const __hip_bfloat16* __restrict__ tf,
    const __hip_bfloat16* __restrict__ P,
    const int* __restrict__ text_length,
    const float* __restrict__ logit_scale,
    float* __restrict__ out)
{
    __shared__ __hip_bfloat16 Blds[G][NPAD][BROW];   // 69632 B
    __shared__ float sums[G][CH_TEXTS];              // 1024 B

    const int ig   = blockIdx.x & 63;   // image group (4 images)
    const int sc   = blockIdx.x >> 6;   // text chunk (64 texts)
    const int tid  = threadIdx.x;
    const int wave = tid >> 6;
    const int lane = tid & 63;
    const int lr   = lane & 15;
    const int lhi  = lane >> 4;

    for (int idx = tid; idx < G * CH_TEXTS; idx += 512)
        (&sums[0][0])[idx] = 0.f;

    // Stage 4 image B-tiles into LDS (16B chunks, padded row stride)
    const __hip_bfloat16* Pg = P + (size_t)(ig * G) * NPAD * NE;
    for (int idx = tid; idx < G * NPAD * NE / 8; idx += 512) {
        int g   = idx >> 10;
        int rem = idx & 1023;
        int p   = rem >> 4;
        int c   = rem & 15;
        bf16x8 v = *reinterpret_cast<const bf16x8*>(Pg + (size_t)(g * NPAD + p) * NE + c * 8);
        *reinterpret_cast<bf16x8*>(&Blds[g][p][c * 8]) = v;
    }
    __syncthreads();

    const __hip_bfloat16* TFc = tf + (size_t)sc * CH_ROWS * NE;

    #pragma unroll 1
    for (int q = wave; q < QUADS; q += 8) {
        const int mbase = q * 64;
        // A fragments for 4 m-tiles x 4 k-steps, straight from global (L2-hot)
        bf16x8 afrag[4][4];
        #pragma unroll
        for (int m = 0; m < 4; m++) {
            const __hip_bfloat16* arow = TFc + (size_t)(mbase + m * 16 + lr) * NE + lhi * 8;
            #pragma unroll
            for (int k = 0; k < 4; k++)
                afrag[m][k] = *reinterpret_cast<const bf16x8*>(arow + k * 32);
        }
        #pragma unroll 1
        for (int g = 0; g < G; g++) {
            f32x4 acc[4][4];
            #pragma unroll
            for (int m = 0; m < 4; m++)
                #pragma unroll
                for (int n = 0; n < 4; n++)
                    acc[m][n] = (f32x4){0.f, 0.f, 0.f, 0.f};
            #pragma unroll
            for (int k = 0; k < 4; k++) {
                #pragma unroll
                for (int n = 0; n < 4; n++) {
                    bf16x8 bfrag = *reinterpret_cast<const bf16x8*>(
                        &Blds[g][n * 16 + lr][k * 32 + lhi * 8]);
                    #pragma unroll
                    for (int m = 0; m < 4; m++)
                        acc[m][n] = __builtin_amdgcn_mfma_f32_16x16x32_bf16(
                            afrag[m][k], bfrag, acc[m][n], 0, 0, 0);
                }
            }
            // Per-row max over 49 patches (mask padded cols), then accumulate per text
            #pragma unroll
            for (int m = 0; m < 4; m++) {
                #pragma unroll
                for (int r = 0; r < 4; r++) {
                    float v = fmaxf(fmaxf(acc[m][0][r], acc[m][1][r]), acc[m][2][r]);
                    float v3 = (lr == 0) ? acc[m][3][r] : -1e30f;  // n-tile 3: only col 48 valid
                    v = fmaxf(v, v3);
                    v = fmaxf(v, __shfl_xor(v, 1));
                    v = fmaxf(v, __shfl_xor(v, 2));
                    v = fmaxf(v, __shfl_xor(v, 4));
                    v = fmaxf(v, __shfl_xor(v, 8));
                    if (lr == 0) {
                        int row = mbase + m * 16 + lhi * 4 + r;   // 0..1599
                        atomicAdd(&sums[g][row / NL], v);
                    }
                }
            }
        }
    }
    __syncthreads();

    // Epilogue: divide by length, scale, write both outputs
    float scale = expf(logit_scale[0]);
    for (int idx = tid; idx < G * CH_TEXTS; idx += 512) {
        int g   = idx >> 6;
        int tl_ = idx & 63;
        int t = sc * CH_TEXTS + tl_;
        int i = ig * G + g;
        float val = sums[g][tl_] / (float)text_length[t] * scale;
        out[(size_t)i * NT + t] = val;                      // logits_per_image [I,T]
        out[(size_t)NI * NT + (size_t)t * NI + i] = val;    // logits_per_text  [T,I]
    }
}

extern "C" void kernel_launch(void* const* d_in, const int* in_sizes, int n_in,
                              void* d_out, int out_size, void* d_ws, size_t ws_size,
                              hipStream_t stream)
{
    const float* img  = (const float*)d_in[0];   // [256,128,7,7]
    const float* emb  = (const float*)d_in[1];   // [10000,128]
    const float* ls   = (const float*)d_in[2];   // scalar
    const int*   text = (const int*)d_in[3];     // [256,25]
    const int*   tlen = (const int*)d_in[4];     // [256]
    float* out = (float*)d_out;

    __hip_bfloat16* tf = (__hip_bfloat16*)d_ws;                              // 1,638,400 B
    __hip_bfloat16* P  = (__hip_bfloat16*)((char*)d_ws + (size_t)NTL * NE * 2); // 4,194,304 B

    gather_tf_kernel<<<NTL * NE / 4 / 256, 256, 0, stream>>>(emb, text, tf);
    prep_img_kernel<<<NI, 256, 0, stream>>>(img, P);
    match_kernel<<<256, 512, 0, stream>>>(tf, P, tlen, ls, out);
}

// Round 2
// 68.434 us; speedup vs baseline: 1.1053x; 1.1053x over previous
//
#include <hip/hip_runtime.h>
#include <hip/hip_bf16.h>

#define NI 256
#define NT 256
#define NL 25
#define NE 128
#define NHW 49
#define NPAD 64
#define NTL (NT*NL)   // 6400

typedef __attribute__((ext_vector_type(8))) short bf16x8;
typedef __attribute__((ext_vector_type(4))) float f32x4;

struct bf4 { __hip_bfloat16 x, y, z, w; };
struct bf2 { __hip_bfloat16 x, y; };

// ---- Kernel 1: gather text features -> bf16 TF[6400][128] ----
__global__ __launch_bounds__(256) void gather_tf_kernel(
    const float* __restrict__ emb, const int* __restrict__ text,
    __hip_bfloat16* __restrict__ tf)
{
    int idx = blockIdx.x * 256 + threadIdx.x;   // 4 elems each
    int tl = idx >> 5;
    int q  = idx & 31;
    int tok = text[tl];
    float4 v = *reinterpret_cast<const float4*>(emb + (size_t)tok * NE + q * 4);
    bf4 o { __float2bfloat16(v.x), __float2bfloat16(v.y),
            __float2bfloat16(v.z), __float2bfloat16(v.w) };
    *reinterpret_cast<bf4*>(tf + (size_t)tl * NE + q * 4) = o;
}

// ---- Kernel 2: transpose image features -> bf16 P[256][64][128] (patch-major, zero-padded) ----
__global__ __launch_bounds__(256) void prep_img_kernel(
    const float* __restrict__ img, __hip_bfloat16* __restrict__ P)
{
    __shared__ float tile[NE * NHW];   // 6272 f32
    int i = blockIdx.x;
    const float* src = img + (size_t)i * NE * NHW;
    for (int idx = threadIdx.x; idx < NE * NHW; idx += 256) tile[idx] = src[idx];
    __syncthreads();
    __hip_bfloat16* dst = P + (size_t)i * NPAD * NE;
    for (int idx = threadIdx.x; idx < NPAD * NE / 2; idx += 256) {
        int p = idx >> 6;
        int e = (idx & 63) * 2;
        bf2 o;
        if (p < NHW) {
            o.x = __float2bfloat16(tile[e * NHW + p]);
            o.y = __float2bfloat16(tile[(e + 1) * NHW + p]);
        } else {
            o.x = __float2bfloat16(0.f);
            o.y = o.x;
        }
        *reinterpret_cast<bf2*>(dst + p * NE + e) = o;
    }
}

// ---- Kernel 3: fused MFMA GEMM (swapped operands) + max + sum + scale ----
// Grid: 1024 WGs = 64 image-groups (4 images) x 16 text-chunks (16 texts = 400 rows).
// Each wave owns one image; all 4 waves sweep the same 25 text tiles (B-frags
// shared via L1). Patches live in 64 VGPRs; D row = patch, D col = text row,
// so max-over-patches is an in-register fmax tree + 2 shfl_xor.
__global__ __launch_bounds__(256, 4) void match_kernel(
    const __hip_bfloat16* __restrict__ tf,
    const __hip_bfloat16* __restrict__ P,
    const int* __restrict__ text_length,
    const float* __restrict__ logit_scale,
    float* __restrict__ out)
{
    __shared__ float sums[4][16];

    const int ig   = blockIdx.x & 63;   // image group (4 images)
    const int tq   = blockIdx.x >> 6;   // text chunk (16 texts = 400 rows = 25 tiles)
    const int tid  = threadIdx.x;
    const int wave = tid >> 6;
    const int lane = tid & 63;
    const int lr   = lane & 15;
    const int lhi  = lane >> 4;

    if (lane < 16) sums[wave][lane] = 0.f;

    // A-fragments: this wave's image, 64 patches x 128 k, in registers.
    const int img = ig * 4 + wave;
    const __hip_bfloat16* Pi = P + (size_t)img * NPAD * NE;
    bf16x8 pfrag[4][4];
    #pragma unroll
    for (int m = 0; m < 4; m++) {
        const __hip_bfloat16* prow = Pi + (size_t)(m * 16 + lr) * NE + lhi * 8;
        #pragma unroll
        for (int k = 0; k < 4; k++)
            pfrag[m][k] = *reinterpret_cast<const bf16x8*>(prow + k * 32);
    }

    const __hip_bfloat16* TFq = tf + (size_t)tq * 400 * NE;

    #pragma unroll 1
    for (int j = 0; j < 25; j++) {
        // B-fragments: 16 text rows (same for all 4 waves -> L1 hits)
        const __hip_bfloat16* trow = TFq + (size_t)(j * 16 + lr) * NE + lhi * 8;
        bf16x8 tfrag[4];
        #pragma unroll
        for (int k = 0; k < 4; k++)
            tfrag[k] = *reinterpret_cast<const bf16x8*>(trow + k * 32);

        f32x4 acc[4];
        #pragma unroll
        for (int m = 0; m < 4; m++) acc[m] = (f32x4){0.f, 0.f, 0.f, 0.f};
        #pragma unroll
        for (int k = 0; k < 4; k++)
            #pragma unroll
            for (int m = 0; m < 4; m++)
                acc[m] = __builtin_amdgcn_mfma_f32_16x16x32_bf16(
                    pfrag[m][k], tfrag[k], acc[m], 0, 0, 0);

        // max over patches: rows are patches (m*16 + lhi*4 + r).
        // m=3 tile: only patch 48 (lhi==0, r==0) is real; rest are zero-pad.
        float x0 = fmaxf(acc[0][0], acc[0][1]);
        float x1 = fmaxf(acc[0][2], acc[0][3]);
        float x2 = fmaxf(acc[1][0], acc[1][1]);
        float x3 = fmaxf(acc[1][2], acc[1][3]);
        float x4 = fmaxf(acc[2][0], acc[2][1]);
        float x5 = fmaxf(acc[2][2], acc[2][3]);
        float x6 = (lhi == 0) ? acc[3][0] : -3e38f;
        x0 = fmaxf(x0, x1);
        x2 = fmaxf(x2, x3);
        x4 = fmaxf(x4, x5);
        x0 = fmaxf(x0, x2);
        x4 = fmaxf(x4, x6);
        float v = fmaxf(x0, x4);
        // combine the 4 row-groups (lanes lr, lr+16, lr+32, lr+48)
        v = fmaxf(v, __shfl_xor(v, 16));
        v = fmaxf(v, __shfl_xor(v, 32));
        if (lane < 16) {
            int row = j * 16 + lane;            // text row within chunk, 0..399
            atomicAdd(&sums[wave][row / NL], v);
        }
    }
    __syncthreads();

    // Epilogue: 64 outputs per WG (4 images x 16 texts), both layouts.
    if (tid < 64) {
        int g  = tid >> 4;
        int tl = tid & 15;
        int t = tq * 16 + tl;
        int i = ig * 4 + g;
        float scale = expf(logit_scale[0]);
        float val = sums[g][tl] / (float)text_length[t] * scale;
        out[(size_t)i * NT + t] = val;                      // logits_per_image [I,T]
        out[(size_t)NI * NT + (size_t)t * NI + i] = val;    // logits_per_text  [T,I]
    }
}

extern "C" void kernel_launch(void* const* d_in, const int* in_sizes, int n_in,
                              void* d_out, int out_size, void* d_ws, size_t ws_size,
                              hipStream_t stream)
{
    const float* img  = (const float*)d_in[0];   // [256,128,7,7]
    const float* emb  = (const float*)d_in[1];   // [10000,128]
    const float* ls   = (const float*)d_in[2];   // scalar
    const int*   text = (const int*)d_in[3];     // [256,25]
    const int*   tlen = (const int*)d_in[4];     // [256]
    float* out = (float*)d_out;

    __hip_bfloat16* tf = (__hip_bfloat16*)d_ws;                                 // 1,638,400 B
    __hip_bfloat16* P  = (__hip_bfloat16*)((char*)d_ws + (size_t)NTL * NE * 2); // 4,194,304 B

    gather_tf_kernel<<<NTL * NE / 4 / 256, 256, 0, stream>>>(emb, text, tf);
    prep_img_kernel<<<NI, 256, 0, stream>>>(img, P);
    match_kernel<<<1024, 256, 0, stream>>>(tf, P, tlen, ls, out);
}

// Round 3
// 66.906 us; speedup vs baseline: 1.1306x; 1.0228x over previous
//
#include <hip/hip_runtime.h>
#include <hip/hip_bf16.h>

#define NI 256
#define NT 256
#define NL 25
#define NE 128
#define NHW 49
#define NPAD 64
#define NTL (NT*NL)   // 6400

typedef __attribute__((ext_vector_type(8))) short bf16x8;
typedef __attribute__((ext_vector_type(4))) float f32x4;

struct bf4 { __hip_bfloat16 x, y, z, w; };
struct bf2 { __hip_bfloat16 x, y; };

// ---- Kernel 1 (merged prep): blocks 0..799 gather text features,
//      blocks 800..1055 transpose image features ----
__global__ __launch_bounds__(256) void prep_kernel(
    const float* __restrict__ emb, const int* __restrict__ text,
    const float* __restrict__ img,
    __hip_bfloat16* __restrict__ tf, __hip_bfloat16* __restrict__ P)
{
    __shared__ float tile[NE * NHW];   // used by image path only (25 KB)

    if (blockIdx.x < 800) {
        // gather: tf[6400][128] = bf16(emb[text[tl]])
        int idx = blockIdx.x * 256 + threadIdx.x;   // 4 elems each
        int tl = idx >> 5;
        int q  = idx & 31;
        int tok = text[tl];
        float4 v = *reinterpret_cast<const float4*>(emb + (size_t)tok * NE + q * 4);
        bf4 o { __float2bfloat16(v.x), __float2bfloat16(v.y),
                __float2bfloat16(v.z), __float2bfloat16(v.w) };
        *reinterpret_cast<bf4*>(tf + (size_t)tl * NE + q * 4) = o;
    } else {
        // transpose: P[256][64][128] patch-major, zero-padded 49->64
        int i = blockIdx.x - 800;
        const float* src = img + (size_t)i * NE * NHW;
        for (int idx = threadIdx.x; idx < NE * NHW; idx += 256) tile[idx] = src[idx];
        __syncthreads();
        __hip_bfloat16* dst = P + (size_t)i * NPAD * NE;
        for (int idx = threadIdx.x; idx < NPAD * NE / 2; idx += 256) {
            int p = idx >> 6;
            int e = (idx & 63) * 2;
            bf2 o;
            if (p < NHW) {
                o.x = __float2bfloat16(tile[e * NHW + p]);
                o.y = __float2bfloat16(tile[(e + 1) * NHW + p]);
            } else {
                o.x = __float2bfloat16(0.f);
                o.y = o.x;
            }
            *reinterpret_cast<bf2*>(dst + p * NE + e) = o;
        }
    }
}

// ---- Kernel 2: fused MFMA GEMM (swapped operands) + max + sum + scale ----
// 1024 WGs = 64 image-groups (4 images) x 16 text-chunks (16 texts = 400 rows).
// Wave = 1 image; patches pinned in 64 VGPRs (asm pin prevents remat);
// B-fragments prefetched one tile ahead. D row = patch, D col = text row.
__global__ __launch_bounds__(256, 4) void match_kernel(
    const __hip_bfloat16* __restrict__ tf,
    const __hip_bfloat16* __restrict__ P,
    const int* __restrict__ text_length,
    const float* __restrict__ logit_scale,
    float* __restrict__ out)
{
    __shared__ float vals[4][25][16];   // per-(wave, text-row-tile, row) max

    const int ig   = blockIdx.x & 63;   // image group (4 images)
    const int tq   = blockIdx.x >> 6;   // text chunk (16 texts = 400 rows = 25 tiles)
    const int tid  = threadIdx.x;
    const int wave = tid >> 6;
    const int lane = tid & 63;
    const int lr   = lane & 15;
    const int lhi  = lane >> 4;

    // A-fragments: this wave's image, 64 patches x 128 k, pinned in registers.
    const int img = ig * 4 + wave;
    const __hip_bfloat16* Pi = P + (size_t)img * NPAD * NE;
    bf16x8 pfrag[4][4];
    #pragma unroll
    for (int m = 0; m < 4; m++) {
        const __hip_bfloat16* prow = Pi + (size_t)(m * 16 + lr) * NE + lhi * 8;
        #pragma unroll
        for (int k = 0; k < 4; k++)
            pfrag[m][k] = *reinterpret_cast<const bf16x8*>(prow + k * 32);
    }
    #pragma unroll
    for (int m = 0; m < 4; m++)
        #pragma unroll
        for (int k = 0; k < 4; k++)
            asm volatile("" : "+v"(pfrag[m][k]));   // opaque: no remat, stays in VGPRs

    const __hip_bfloat16* TFq = tf + (size_t)tq * 400 * NE;

    // prefetch tile 0
    bf16x8 tcur[4];
    {
        const __hip_bfloat16* trow = TFq + (size_t)lr * NE + lhi * 8;
        #pragma unroll
        for (int k = 0; k < 4; k++)
            tcur[k] = *reinterpret_cast<const bf16x8*>(trow + k * 32);
    }

    #pragma unroll 1
    for (int j = 0; j < 25; j++) {
        // prefetch next tile (clamped; last iter re-loads tile 24, unused cost)
        int jn = (j < 24) ? j + 1 : 24;
        const __hip_bfloat16* trow = TFq + (size_t)(jn * 16 + lr) * NE + lhi * 8;
        bf16x8 tnxt[4];
        #pragma unroll
        for (int k = 0; k < 4; k++)
            tnxt[k] = *reinterpret_cast<const bf16x8*>(trow + k * 32);

        f32x4 acc[4];
        #pragma unroll
        for (int m = 0; m < 4; m++) acc[m] = (f32x4){0.f, 0.f, 0.f, 0.f};
        #pragma unroll
        for (int k = 0; k < 4; k++)
            #pragma unroll
            for (int m = 0; m < 4; m++)
                acc[m] = __builtin_amdgcn_mfma_f32_16x16x32_bf16(
                    pfrag[m][k], tcur[k], acc[m], 0, 0, 0);

        // max over patches: rows are patches (m*16 + lhi*4 + r).
        // m=3 tile: only patch 48 (lhi==0, reg 0) is real; rest zero-pad.
        float x0 = fmaxf(acc[0][0], acc[0][1]);
        float x1 = fmaxf(acc[0][2], acc[0][3]);
        float x2 = fmaxf(acc[1][0], acc[1][1]);
        float x3 = fmaxf(acc[1][2], acc[1][3]);
        float x4 = fmaxf(acc[2][0], acc[2][1]);
        float x5 = fmaxf(acc[2][2], acc[2][3]);
        float x6 = (lhi == 0) ? acc[3][0] : -3e38f;
        x0 = fmaxf(x0, x1);
        x2 = fmaxf(x2, x3);
        x4 = fmaxf(x4, x5);
        x0 = fmaxf(x0, x2);
        x4 = fmaxf(x4, x6);
        float v = fmaxf(x0, x4);
        v = fmaxf(v, __shfl_xor(v, 16));
        v = fmaxf(v, __shfl_xor(v, 32));
        if (lane < 16) vals[wave][j][lane] = v;

        #pragma unroll
        for (int k = 0; k < 4; k++) tcur[k] = tnxt[k];
    }
    __syncthreads();

    // Epilogue: 64 outputs per WG (4 images x 16 texts), both layouts.
    if (tid < 64) {
        int g  = tid >> 4;
        int tl = tid & 15;
        float s = 0.f;
        #pragma unroll
        for (int l = 0; l < 25; l++) {
            int row = tl * 25 + l;              // text row within chunk
            s += vals[g][row >> 4][row & 15];
        }
        int t = tq * 16 + tl;
        int i = ig * 4 + g;
        float val = s / (float)text_length[t] * expf(logit_scale[0]);
        out[(size_t)i * NT + t] = val;                      // logits_per_image [I,T]
        out[(size_t)NI * NT + (size_t)t * NI + i] = val;    // logits_per_text  [T,I]
    }
}

extern "C" void kernel_launch(void* const* d_in, const int* in_sizes, int n_in,
                              void* d_out, int out_size, void* d_ws, size_t ws_size,
                              hipStream_t stream)
{
    const float* img  = (const float*)d_in[0];   // [256,128,7,7]
    const float* emb  = (const float*)d_in[1];   // [10000,128]
    const float* ls   = (const float*)d_in[2];   // scalar
    const int*   text = (const int*)d_in[3];     // [256,25]
    const int*   tlen = (const int*)d_in[4];     // [256]
    float* out = (float*)d_out;

    __hip_bfloat16* tf = (__hip_bfloat16*)d_ws;                                 // 1,638,400 B
    __hip_bfloat16* P  = (__hip_bfloat16*)((char*)d_ws + (size_t)NTL * NE * 2); // 4,194,304 B

    prep_kernel<<<800 + NI, 256, 0, stream>>>(emb, text, img, tf, P);
    match_kernel<<<1024, 256, 0, stream>>>(tf, P, tlen, ls, out);
}